// Round 5
// baseline (1250.799 us; speedup 1.0000x reference)
//
#include <hip/hip_runtime.h>
#include <hip/hip_bf16.h>
#include <stdint.h>

typedef unsigned short ushort_t;
typedef float   f32x4  __attribute__((ext_vector_type(4)));
typedef short   bf16x8 __attribute__((ext_vector_type(8)));

#define NSRC 8192
#define NTGT 16384
#define LDP  56   /* ushort stride (112B) for GEMM LDS tiles */

__device__ __forceinline__ ushort_t f2bf(float f){
  union { float f; uint32_t u; } v; v.f = f;
  uint32_t r = v.u + 0x7fffu + ((v.u >> 16) & 1u);
  return (ushort_t)(r >> 16);
}
__device__ __forceinline__ uint2 pack4(f32x4 v){
  uint2 r;
  r.x = (uint32_t)f2bf(v.x) | ((uint32_t)f2bf(v.y) << 16);
  r.y = (uint32_t)f2bf(v.z) | ((uint32_t)f2bf(v.w) << 16);
  return r;
}

// ---------------- generic f32 -> bf16 transpose: D[c][r] = bf16(S[r][c]) ----------------
__global__ __launch_bounds__(256) void k_wt(const float* __restrict__ S, ushort_t* __restrict__ D,
                                            int R, int C){
  __shared__ float tile[32][33];
  const int cb = blockIdx.x * 32, rb = blockIdx.y * 32;
  const int tx = threadIdx.x & 31, ty = threadIdx.x >> 5;
#pragma unroll
  for (int i = 0; i < 4; ++i)
    tile[ty + 8*i][tx] = S[(size_t)(rb + ty + 8*i) * C + cb + tx];
  __syncthreads();
#pragma unroll
  for (int i = 0; i < 4; ++i)
    D[(size_t)(cb + ty + 8*i) * R + rb + tx] = f2bf(tile[tx][ty + 8*i]);
}

// ---------------- B2t tail: row 128 = ones (colsum trick), rows 129..159 = 0 ----------------
__global__ void k_init_b2t_tail(ushort_t* __restrict__ B2t){
  int idx = blockIdx.x * 256 + threadIdx.x;     // 32*16384 total
  int r = idx >> 14;
  int k = idx & 16383;
  B2t[(size_t)(128 + r) * NTGT + k] = (r == 0) ? (ushort_t)0x3F80 : (ushort_t)0;
}

// ---------------- G1: P2[kc] = bf16(A) @ H  (BM=32, BN=256, BK=32, Ksplit=2) + rowsum ----------------
__global__ __launch_bounds__(256, 4) void k_gemm1(const float* __restrict__ A,
    const ushort_t* __restrict__ B1t, float* __restrict__ P2, float* __restrict__ rowsumP){
  __shared__ ushort_t Asl[32 * LDP];
  __shared__ ushort_t Bsl[256 * LDP];
  const int t = threadIdx.x;
  const int mb = blockIdx.x, kc = blockIdx.y;
  const size_t m0 = (size_t)mb * 32;
  const int k0 = kc * 4096;

  const int arow = t >> 3;            // 0..31
  const int acol = (t & 7) * 4;       // 0..28
  float rs = 0.f;

  const int w = t >> 6, lane = t & 63;
  const int wr = w >> 1, wc = w & 1;
  const int fr = lane & 15, q = lane >> 4;

  int bn_[4], bk_[4];
#pragma unroll
  for (int r = 0; r < 4; ++r){
    int c = t + 256 * r; bn_[r] = c >> 2; bk_[r] = (c & 3) * 8;
  }

  f32x4 acc[8];
  const f32x4 vz = {0.f, 0.f, 0.f, 0.f};
#pragma unroll
  for (int j = 0; j < 8; ++j) acc[j] = vz;

  // prefetch kt=0
  f32x4 av = *(const f32x4*)&A[(m0 + arow) * (size_t)NSRC + k0 + acol];
  uint4 bv[4];
#pragma unroll
  for (int r = 0; r < 4; ++r)
    bv[r] = *(const uint4*)&B1t[(size_t)bn_[r] * NSRC + k0 + bk_[r]];

  for (int kt = 0; kt < 128; ++kt){
    __syncthreads();
    *(uint2*)&Asl[arow * LDP + acol] = pack4(av);
#pragma unroll
    for (int r = 0; r < 4; ++r) *(uint4*)&Bsl[bn_[r] * LDP + bk_[r]] = bv[r];
    rs += av.x + av.y + av.z + av.w;
    if (kt < 127){
      const int kk = k0 + (kt + 1) * 32;
      av = *(const f32x4*)&A[(m0 + arow) * (size_t)NSRC + kk + acol];
#pragma unroll
      for (int r = 0; r < 4; ++r)
        bv[r] = *(const uint4*)&B1t[(size_t)bn_[r] * NSRC + kk + bk_[r]];
    }
    __syncthreads();

    bf16x8 af = *(const bf16x8*)&Asl[(wr * 16 + fr) * LDP + q * 8];
#pragma unroll
    for (int fn = 0; fn < 8; ++fn){
      bf16x8 bfv = *(const bf16x8*)&Bsl[(wc * 128 + fn * 16 + fr) * LDP + q * 8];
      acc[fn] = __builtin_amdgcn_mfma_f32_16x16x32_bf16(af, bfv, acc[fn], 0, 0, 0);
    }
  }

  float* Pd = P2 + (size_t)kc * NTGT * 256;
#pragma unroll
  for (int j = 0; j < 4; ++j){
    int row = wr * 16 + q * 4 + j;
#pragma unroll
    for (int fn = 0; fn < 8; ++fn)
      Pd[(m0 + row) * 256 + wc * 128 + fn * 16 + fr] = acc[fn][j];
  }

  // rowsum: 8 lanes (same arow) hold partial sums
  rs += __shfl_xor(rs, 1, 8);
  rs += __shfl_xor(rs, 2, 8);
  rs += __shfl_xor(rs, 4, 8);
  if ((t & 7) == 0)
    rowsumP[(size_t)kc * NTGT + m0 + arow] = rs;
}

// ---------------- G2: G2p[kc] = bf16(A)^T @ [h_tgt|1|0]  (BM=32, BN=160, BK=32, Ksplit=4) ----------------
// A^T fragment built directly in registers from coalesced column loads (no LDS for A).
__global__ __launch_bounds__(256, 4) void k_gemm2(const float* __restrict__ A,
    const ushort_t* __restrict__ B2t, float* __restrict__ G2p){
  __shared__ ushort_t Btl[160 * LDP];
  const int t = threadIdx.x;
  const int sb = blockIdx.x, kc = blockIdx.y;
  const size_t s0 = (size_t)sb * 32;
  const int k0 = kc * 4096;

  const int w = t >> 6, lane = t & 63;
  const int wr = w >> 1, wc = w & 1;
  const int fr = lane & 15, q = lane >> 4;
  const size_t scol = s0 + wr * 16 + fr;
  const int q8 = q * 8;

  int bn_[3], bk_[3];
#pragma unroll
  for (int r = 0; r < 3; ++r){
    int c = t + 256 * r; bn_[r] = c >> 2; bk_[r] = (c & 3) * 8;
  }

  f32x4 acc[5];
  const f32x4 vz = {0.f, 0.f, 0.f, 0.f};
#pragma unroll
  for (int j = 0; j < 5; ++j) acc[j] = vz;

  // prefetch kt=0
  float ar[8];
#pragma unroll
  for (int j = 0; j < 8; ++j)
    ar[j] = A[(size_t)(k0 + q8 + j) * NSRC + scol];
  uint4 bv0, bv1, bv2;
  bv0 = *(const uint4*)&B2t[(size_t)bn_[0] * NTGT + k0 + bk_[0]];
  bv1 = *(const uint4*)&B2t[(size_t)bn_[1] * NTGT + k0 + bk_[1]];
  if (t < 128) bv2 = *(const uint4*)&B2t[(size_t)bn_[2] * NTGT + k0 + bk_[2]];

  for (int kt = 0; kt < 128; ++kt){
    __syncthreads();
    *(uint4*)&Btl[bn_[0] * LDP + bk_[0]] = bv0;
    *(uint4*)&Btl[bn_[1] * LDP + bk_[1]] = bv1;
    if (t < 128) *(uint4*)&Btl[bn_[2] * LDP + bk_[2]] = bv2;
    bf16x8 af;
#pragma unroll
    for (int j = 0; j < 8; ++j) af[j] = (short)f2bf(ar[j]);
    if (kt < 127){
      const int kk = k0 + (kt + 1) * 32;
#pragma unroll
      for (int j = 0; j < 8; ++j)
        ar[j] = A[(size_t)(kk + q8 + j) * NSRC + scol];
      bv0 = *(const uint4*)&B2t[(size_t)bn_[0] * NTGT + kk + bk_[0]];
      bv1 = *(const uint4*)&B2t[(size_t)bn_[1] * NTGT + kk + bk_[1]];
      if (t < 128) bv2 = *(const uint4*)&B2t[(size_t)bn_[2] * NTGT + kk + bk_[2]];
    }
    __syncthreads();

#pragma unroll
    for (int fn = 0; fn < 5; ++fn){
      bf16x8 bfv = *(const bf16x8*)&Btl[(wc * 80 + fn * 16 + fr) * LDP + q * 8];
      acc[fn] = __builtin_amdgcn_mfma_f32_16x16x32_bf16(af, bfv, acc[fn], 0, 0, 0);
    }
  }

  float* Pd = G2p + (size_t)kc * NSRC * 160;
#pragma unroll
  for (int j = 0; j < 4; ++j){
    int row = wr * 16 + q * 4 + j;
#pragma unroll
    for (int fn = 0; fn < 5; ++fn)
      Pd[(s0 + row) * 160 + wc * 80 + fn * 16 + fr] = acc[fn][j];
  }
}

// ---------------- G3: G3p[kc] = bf16(A) @ h_src  (BM=32, BN=128, BK=32, Ksplit=2) ----------------
__global__ __launch_bounds__(256, 4) void k_gemm3(const float* __restrict__ A,
    const ushort_t* __restrict__ B3t, float* __restrict__ G3p){
  __shared__ ushort_t Asl[32 * LDP];
  __shared__ ushort_t Bsl[128 * LDP];
  const int t = threadIdx.x;
  const int mb = blockIdx.x, kc = blockIdx.y;
  const size_t m0 = (size_t)mb * 32;
  const int k0 = kc * 4096;

  const int arow = t >> 3, acol = (t & 7) * 4;
  const int w = t >> 6, lane = t & 63;
  const int wr = w >> 1, wc = w & 1;
  const int fr = lane & 15, q = lane >> 4;

  int bn_[2], bk_[2];
#pragma unroll
  for (int r = 0; r < 2; ++r){
    int c = t + 256 * r; bn_[r] = c >> 2; bk_[r] = (c & 3) * 8;
  }

  f32x4 acc[4];
  const f32x4 vz = {0.f, 0.f, 0.f, 0.f};
#pragma unroll
  for (int j = 0; j < 4; ++j) acc[j] = vz;

  f32x4 av = *(const f32x4*)&A[(m0 + arow) * (size_t)NSRC + k0 + acol];
  uint4 bv[2];
#pragma unroll
  for (int r = 0; r < 2; ++r)
    bv[r] = *(const uint4*)&B3t[(size_t)bn_[r] * NSRC + k0 + bk_[r]];

  for (int kt = 0; kt < 128; ++kt){
    __syncthreads();
    *(uint2*)&Asl[arow * LDP + acol] = pack4(av);
#pragma unroll
    for (int r = 0; r < 2; ++r) *(uint4*)&Bsl[bn_[r] * LDP + bk_[r]] = bv[r];
    if (kt < 127){
      const int kk = k0 + (kt + 1) * 32;
      av = *(const f32x4*)&A[(m0 + arow) * (size_t)NSRC + kk + acol];
#pragma unroll
      for (int r = 0; r < 2; ++r)
        bv[r] = *(const uint4*)&B3t[(size_t)bn_[r] * NSRC + kk + bk_[r]];
    }
    __syncthreads();

    bf16x8 af = *(const bf16x8*)&Asl[(wr * 16 + fr) * LDP + q * 8];
#pragma unroll
    for (int fn = 0; fn < 4; ++fn){
      bf16x8 bfv = *(const bf16x8*)&Bsl[(wc * 64 + fn * 16 + fr) * LDP + q * 8];
      acc[fn] = __builtin_amdgcn_mfma_f32_16x16x32_bf16(af, bfv, acc[fn], 0, 0, 0);
    }
  }

  float* Pd = G3p + (size_t)kc * NTGT * 128;
#pragma unroll
  for (int j = 0; j < 4; ++j){
    int row = wr * 16 + q * 4 + j;
#pragma unroll
    for (int fn = 0; fn < 4; ++fn)
      Pd[(m0 + row) * 128 + wc * 64 + fn * 16 + fr] = acc[fn][j];
  }
}

// ---------------- S1: h_tgt = relu(BN0((P/rowsum)@W0+b0)) -> B2t rows 0..127 (transposed) ----------------
__global__ __launch_bounds__(256) void k_s1(
    const float* __restrict__ P2, const float* __restrict__ rowsumP,
    const ushort_t* __restrict__ W0t, const float* __restrict__ b0,
    const float* __restrict__ g, const float* __restrict__ be,
    const float* __restrict__ mu, const float* __restrict__ va,
    ushort_t* __restrict__ B2t)
{
  __shared__ ushort_t Xs[64 * 72];
  __shared__ ushort_t Ws[128 * 72];
  __shared__ float    os[64 * 132];
  __shared__ float invs[64], scs[128], mbs[128];
  const int t = threadIdx.x;
  const size_t m0 = (size_t)blockIdx.x * 64;

  if (t < 64){
    float rsv = rowsumP[m0 + t] + rowsumP[(size_t)NTGT + m0 + t];
    invs[t] = 1.0f / fmaxf(rsv, 1e-8f);
  } else if (t < 192){
    int n = t - 64;
    float s = g[n] * rsqrtf(va[n] + 1e-5f);
    scs[n] = s;
    mbs[n] = (b0[n] - mu[n]) * s + be[n];
  }
  __syncthreads();

  const int w = t >> 6, lane = t & 63;
  const int wr = w >> 1, wc = w & 1;
  const int fr = lane & 15, q = lane >> 4;
  f32x4 acc[2][4];
  const f32x4 vz = {0.f, 0.f, 0.f, 0.f};
#pragma unroll
  for (int i = 0; i < 2; ++i)
#pragma unroll
    for (int j = 0; j < 4; ++j) acc[i][j] = vz;

  for (int kt = 0; kt < 4; ++kt){
    const int kk = kt * 64;
    __syncthreads();
#pragma unroll
    for (int r = 0; r < 4; ++r){
      int c = t + 256 * r;
      int row = c >> 4, col4 = (c & 15) * 4;
      const float* pa = &P2[(m0 + row) * 256 + kk + col4];
      f32x4 v0 = *(const f32x4*)pa;
      f32x4 v1 = *(const f32x4*)(pa + (size_t)NTGT * 256);
      f32x4 v = (v0 + v1) * invs[row];
      *(uint2*)&Xs[row * 72 + col4] = pack4(v);
    }
#pragma unroll
    for (int r = 0; r < 4; ++r){
      int c = t + 256 * r;
      int n = c >> 3, k8 = (c & 7) * 8;
      *(uint4*)&Ws[n * 72 + k8] = *(const uint4*)&W0t[(size_t)n * 256 + kk + k8];
    }
    __syncthreads();
#pragma unroll
    for (int ks = 0; ks < 2; ++ks){
      bf16x8 af[2], bfv[4];
      af[0] = *(const bf16x8*)&Xs[(wr * 32 + fr) * 72 + ks * 32 + q * 8];
      af[1] = *(const bf16x8*)&Xs[(wr * 32 + 16 + fr) * 72 + ks * 32 + q * 8];
#pragma unroll
      for (int fn = 0; fn < 4; ++fn)
        bfv[fn] = *(const bf16x8*)&Ws[(wc * 64 + fn * 16 + fr) * 72 + ks * 32 + q * 8];
#pragma unroll
      for (int fm = 0; fm < 2; ++fm)
#pragma unroll
        for (int fn = 0; fn < 4; ++fn)
          acc[fm][fn] = __builtin_amdgcn_mfma_f32_16x16x32_bf16(af[fm], bfv[fn], acc[fm][fn], 0, 0, 0);
    }
  }

#pragma unroll
  for (int fm = 0; fm < 2; ++fm)
#pragma unroll
    for (int fn = 0; fn < 4; ++fn){
      int n = wc * 64 + fn * 16 + fr;
      float s = scs[n], mb = mbs[n];
#pragma unroll
      for (int j = 0; j < 4; ++j){
        int row = wr * 32 + fm * 16 + q * 4 + j;
        os[row * 132 + n] = fmaxf(acc[fm][fn][j] * s + mb, 0.f);
      }
    }
  __syncthreads();
  {
    int nn = t >> 1, mc = (t & 1) * 32;
    ushort_t buf[32];
#pragma unroll
    for (int i = 0; i < 32; ++i) buf[i] = f2bf(os[(mc + i) * 132 + nn]);
    uint4* dst = (uint4*)&B2t[(size_t)nn * NTGT + m0 + mc];
    dst[0] = *(uint4*)&buf[0];  dst[1] = *(uint4*)&buf[8];
    dst[2] = *(uint4*)&buf[16]; dst[3] = *(uint4*)&buf[24];
  }
}

// ---------------- S2: h_src = relu(BNb((Q/colsum)@Wb0+bb0)) -> B3t (transposed) ----------------
__global__ __launch_bounds__(256) void k_s2(
    const float* __restrict__ G2p,
    const ushort_t* __restrict__ Wb0t, const float* __restrict__ bb0,
    const float* __restrict__ g, const float* __restrict__ be,
    const float* __restrict__ mu, const float* __restrict__ va,
    ushort_t* __restrict__ B3t)
{
  __shared__ ushort_t Xs[64 * 72];
  __shared__ ushort_t Ws[128 * 72];
  __shared__ float    os[64 * 132];
  __shared__ float invs[64], scs[128], mbs[128];
  const int t = threadIdx.x;
  const size_t m0 = (size_t)blockIdx.x * 64;
  const size_t CH = (size_t)NSRC * 160;

  if (t < 64){
    size_t row = m0 + t;
    float c = G2p[row * 160 + 128] + G2p[CH + row * 160 + 128]
            + G2p[2 * CH + row * 160 + 128] + G2p[3 * CH + row * 160 + 128];
    invs[t] = 1.0f / fmaxf(c, 1e-8f);
  } else if (t < 192){
    int n = t - 64;
    float s = g[n] * rsqrtf(va[n] + 1e-5f);
    scs[n] = s;
    mbs[n] = (bb0[n] - mu[n]) * s + be[n];
  }
  __syncthreads();

  const int w = t >> 6, lane = t & 63;
  const int wr = w >> 1, wc = w & 1;
  const int fr = lane & 15, q = lane >> 4;
  f32x4 acc[2][4];
  const f32x4 vz = {0.f, 0.f, 0.f, 0.f};
#pragma unroll
  for (int i = 0; i < 2; ++i)
#pragma unroll
    for (int j = 0; j < 4; ++j) acc[i][j] = vz;

  for (int kt = 0; kt < 2; ++kt){
    const int kk = kt * 64;
    __syncthreads();
#pragma unroll
    for (int r = 0; r < 4; ++r){
      int c = t + 256 * r;
      int row = c >> 4, col4 = (c & 15) * 4;
      const float* pa = &G2p[(m0 + row) * 160 + kk + col4];
      f32x4 v0 = *(const f32x4*)pa;
      f32x4 v1 = *(const f32x4*)(pa + CH);
      f32x4 v2 = *(const f32x4*)(pa + 2 * CH);
      f32x4 v3 = *(const f32x4*)(pa + 3 * CH);
      f32x4 v = (v0 + v1 + v2 + v3) * invs[row];
      *(uint2*)&Xs[row * 72 + col4] = pack4(v);
    }
#pragma unroll
    for (int r = 0; r < 4; ++r){
      int c = t + 256 * r;
      int n = c >> 3, k8 = (c & 7) * 8;
      *(uint4*)&Ws[n * 72 + k8] = *(const uint4*)&Wb0t[(size_t)n * 128 + kk + k8];
    }
    __syncthreads();
#pragma unroll
    for (int ks = 0; ks < 2; ++ks){
      bf16x8 af[2], bfv[4];
      af[0] = *(const bf16x8*)&Xs[(wr * 32 + fr) * 72 + ks * 32 + q * 8];
      af[1] = *(const bf16x8*)&Xs[(wr * 32 + 16 + fr) * 72 + ks * 32 + q * 8];
#pragma unroll
      for (int fn = 0; fn < 4; ++fn)
        bfv[fn] = *(const bf16x8*)&Ws[(wc * 64 + fn * 16 + fr) * 72 + ks * 32 + q * 8];
#pragma unroll
      for (int fm = 0; fm < 2; ++fm)
#pragma unroll
        for (int fn = 0; fn < 4; ++fn)
          acc[fm][fn] = __builtin_amdgcn_mfma_f32_16x16x32_bf16(af[fm], bfv[fn], acc[fm][fn], 0, 0, 0);
    }
  }

#pragma unroll
  for (int fm = 0; fm < 2; ++fm)
#pragma unroll
    for (int fn = 0; fn < 4; ++fn){
      int n = wc * 64 + fn * 16 + fr;
      float s = scs[n], mb = mbs[n];
#pragma unroll
      for (int j = 0; j < 4; ++j){
        int row = wr * 32 + fm * 16 + q * 4 + j;
        os[row * 132 + n] = fmaxf(acc[fm][fn][j] * s + mb, 0.f);
      }
    }
  __syncthreads();
  {
    int nn = t >> 1, mc = (t & 1) * 32;
    ushort_t buf[32];
#pragma unroll
    for (int i = 0; i < 32; ++i) buf[i] = f2bf(os[(mc + i) * 132 + nn]);
    uint4* dst = (uint4*)&B3t[(size_t)nn * NSRC + m0 + mc];
    dst[0] = *(uint4*)&buf[0];  dst[1] = *(uint4*)&buf[8];
    dst[2] = *(uint4*)&buf[16]; dst[3] = *(uint4*)&buf[24];
  }
}

// ---------------- S3: y=relu(BN1((R/rowsum)@W1+b1)); out = y@Wout + bout ----------------
__global__ __launch_bounds__(256) void k_s3(
    const float* __restrict__ G3p, const float* __restrict__ rowsumP,
    const ushort_t* __restrict__ W1t, const float* __restrict__ b1,
    const float* __restrict__ g, const float* __restrict__ be,
    const float* __restrict__ mu, const float* __restrict__ va,
    const ushort_t* __restrict__ Woutt, const float* __restrict__ bout,
    float* __restrict__ out)
{
  __shared__ ushort_t Xs[64 * 72];
  __shared__ ushort_t Ws[128 * 72];
  __shared__ ushort_t ys[64 * 136];
  __shared__ ushort_t Ws2[64 * 136];
  __shared__ float invs[64], scs[128], mbs[128];
  const int t = threadIdx.x;
  const size_t m0 = (size_t)blockIdx.x * 64;
  const size_t CH = (size_t)NTGT * 128;

  if (t < 64){
    float rsv = rowsumP[m0 + t] + rowsumP[(size_t)NTGT + m0 + t];
    invs[t] = 1.0f / fmaxf(rsv, 1e-8f);
  } else if (t < 192){
    int n = t - 64;
    float s = g[n] * rsqrtf(va[n] + 1e-5f);
    scs[n] = s;
    mbs[n] = (b1[n] - mu[n]) * s + be[n];
  }
#pragma unroll
  for (int r = 0; r < 4; ++r){
    int c = t + 256 * r;
    int n = c >> 4, k8 = (c & 15) * 8;
    *(uint4*)&Ws2[n * 136 + k8] = *(const uint4*)&Woutt[(size_t)n * 128 + k8];
  }
  __syncthreads();

  const int w = t >> 6, lane = t & 63;
  const int wr = w >> 1, wc = w & 1;
  const int fr = lane & 15, q = lane >> 4;
  f32x4 acc[2][4];
  const f32x4 vz = {0.f, 0.f, 0.f, 0.f};
#pragma unroll
  for (int i = 0; i < 2; ++i)
#pragma unroll
    for (int j = 0; j < 4; ++j) acc[i][j] = vz;

  for (int kt = 0; kt < 2; ++kt){
    const int kk = kt * 64;
    __syncthreads();
#pragma unroll
    for (int r = 0; r < 4; ++r){
      int c = t + 256 * r;
      int row = c >> 4, col4 = (c & 15) * 4;
      const float* pa = &G3p[(m0 + row) * 128 + kk + col4];
      f32x4 v0 = *(const f32x4*)pa;
      f32x4 v1 = *(const f32x4*)(pa + CH);
      f32x4 v = (v0 + v1) * invs[row];
      *(uint2*)&Xs[row * 72 + col4] = pack4(v);
    }
#pragma unroll
    for (int r = 0; r < 4; ++r){
      int c = t + 256 * r;
      int n = c >> 3, k8 = (c & 7) * 8;
      *(uint4*)&Ws[n * 72 + k8] = *(const uint4*)&W1t[(size_t)n * 128 + kk + k8];
    }
    __syncthreads();
#pragma unroll
    for (int ks = 0; ks < 2; ++ks){
      bf16x8 af[2], bfv[4];
      af[0] = *(const bf16x8*)&Xs[(wr * 32 + fr) * 72 + ks * 32 + q * 8];
      af[1] = *(const bf16x8*)&Xs[(wr * 32 + 16 + fr) * 72 + ks * 32 + q * 8];
#pragma unroll
      for (int fn = 0; fn < 4; ++fn)
        bfv[fn] = *(const bf16x8*)&Ws[(wc * 64 + fn * 16 + fr) * 72 + ks * 32 + q * 8];
#pragma unroll
      for (int fm = 0; fm < 2; ++fm)
#pragma unroll
        for (int fn = 0; fn < 4; ++fn)
          acc[fm][fn] = __builtin_amdgcn_mfma_f32_16x16x32_bf16(af[fm], bfv[fn], acc[fm][fn], 0, 0, 0);
    }
  }

#pragma unroll
  for (int fm = 0; fm < 2; ++fm)
#pragma unroll
    for (int fn = 0; fn < 4; ++fn){
      int n = wc * 64 + fn * 16 + fr;
      float s = scs[n], mb = mbs[n];
#pragma unroll
      for (int j = 0; j < 4; ++j){
        int row = wr * 32 + fm * 16 + q * 4 + j;
        ys[row * 136 + n] = f2bf(fmaxf(acc[fm][fn][j] * s + mb, 0.f));
      }
    }
  __syncthreads();

  f32x4 acc2[2][2];
#pragma unroll
  for (int i = 0; i < 2; ++i)
#pragma unroll
    for (int j = 0; j < 2; ++j) acc2[i][j] = vz;
#pragma unroll
  for (int ks = 0; ks < 4; ++ks){
    bf16x8 af[2], bfv[2];
    af[0] = *(const bf16x8*)&ys[(wr * 32 + fr) * 136 + ks * 32 + q * 8];
    af[1] = *(const bf16x8*)&ys[(wr * 32 + 16 + fr) * 136 + ks * 32 + q * 8];
#pragma unroll
    for (int fn = 0; fn < 2; ++fn)
      bfv[fn] = *(const bf16x8*)&Ws2[(wc * 32 + fn * 16 + fr) * 136 + ks * 32 + q * 8];
#pragma unroll
    for (int fm = 0; fm < 2; ++fm)
#pragma unroll
      for (int fn = 0; fn < 2; ++fn)
        acc2[fm][fn] = __builtin_amdgcn_mfma_f32_16x16x32_bf16(af[fm], bfv[fn], acc2[fm][fn], 0, 0, 0);
  }
#pragma unroll
  for (int fm = 0; fm < 2; ++fm)
#pragma unroll
    for (int fn = 0; fn < 2; ++fn){
      int n = wc * 32 + fn * 16 + fr;
      float bo = bout[n];
#pragma unroll
      for (int j = 0; j < 4; ++j){
        int row = wr * 32 + fm * 16 + q * 4 + j;
        out[(m0 + row) * 64 + n] = acc2[fm][fn][j] + bo;
      }
    }
}

// ---------------- launch ----------------
extern "C" void kernel_launch(void* const* d_in, const int* in_sizes, int n_in,
                              void* d_out, int out_size, void* d_ws, size_t ws_size,
                              hipStream_t stream) {
  const float* Hs  = (const float*)d_in[0];
  const float* A   = (const float*)d_in[2];
  const float* W0  = (const float*)d_in[3];
  const float* b0  = (const float*)d_in[4];
  const float* Wb0 = (const float*)d_in[5];
  const float* bb0 = (const float*)d_in[6];
  const float* W1  = (const float*)d_in[7];
  const float* b1  = (const float*)d_in[8];
  const float* bnfg= (const float*)d_in[9];
  const float* bnfb= (const float*)d_in[10];
  const float* bnfm= (const float*)d_in[11];
  const float* bnfv= (const float*)d_in[12];
  const float* bnbg= (const float*)d_in[13];
  const float* bnbb= (const float*)d_in[14];
  const float* bnbm= (const float*)d_in[15];
  const float* bnbv= (const float*)d_in[16];
  const float* Wout= (const float*)d_in[17];
  const float* bout= (const float*)d_in[18];
  float* out = (float*)d_out;

  char* ws = (char*)d_ws;
  // region R1 (32MB) shared sequentially by P2 (33.5MB) -> G2p (21MB) -> G3p (16.8MB)
  float*    R1    = (float*)ws;
  constexpr size_t OFF_B1T  = 33554432;               // P2 max: 2*16384*256*4
  constexpr size_t OFF_B2T  = OFF_B1T + 4194304;      // B1t: 256*8192*2
  constexpr size_t OFF_B3T  = OFF_B2T + 5242880;      // B2t: 160*16384*2
  constexpr size_t OFF_RS   = OFF_B3T + 2097152;      // B3t: 128*8192*2
  constexpr size_t OFF_W0T  = OFF_RS  + 131072;       // rs: 2*16384*4
  constexpr size_t OFF_WB0T = OFF_W0T + 65536;
  constexpr size_t OFF_W1T  = OFF_WB0T + 32768;
  constexpr size_t OFF_WOT  = OFF_W1T + 32768;
  ushort_t* B1t  = (ushort_t*)(ws + OFF_B1T);
  ushort_t* B2t  = (ushort_t*)(ws + OFF_B2T);
  ushort_t* B3t  = (ushort_t*)(ws + OFF_B3T);
  float*    rsP  = (float*)   (ws + OFF_RS);
  ushort_t* W0t  = (ushort_t*)(ws + OFF_W0T);
  ushort_t* Wb0t = (ushort_t*)(ws + OFF_WB0T);
  ushort_t* W1t  = (ushort_t*)(ws + OFF_W1T);
  ushort_t* Wott = (ushort_t*)(ws + OFF_WOT);

  k_wt<<<dim3(256/32, 8192/32), 256, 0, stream>>>(Hs,  B1t, 8192, 256);
  k_wt<<<dim3(128/32, 256/32),  256, 0, stream>>>(W0,  W0t, 256, 128);
  k_wt<<<dim3(128/32, 128/32),  256, 0, stream>>>(Wb0, Wb0t, 128, 128);
  k_wt<<<dim3(128/32, 128/32),  256, 0, stream>>>(W1,  W1t, 128, 128);
  k_wt<<<dim3(64/32, 128/32),   256, 0, stream>>>(Wout, Wott, 128, 64);
  k_init_b2t_tail<<<2048, 256, 0, stream>>>(B2t);

  k_gemm1<<<dim3(512, 2), 256, 0, stream>>>(A, B1t, R1, rsP);
  k_s1<<<256, 256, 0, stream>>>(R1, rsP, W0t, b0, bnfg, bnfb, bnfm, bnfv, B2t);
  k_gemm2<<<dim3(256, 4), 256, 0, stream>>>(A, B2t, R1);
  k_s2<<<128, 256, 0, stream>>>(R1, Wb0t, bb0, bnbg, bnbb, bnbm, bnbv, B3t);
  k_gemm3<<<dim3(512, 2), 256, 0, stream>>>(A, B3t, R1);
  k_s3<<<256, 256, 0, stream>>>(R1, rsP, W1t, b1, bnfg + 128, bnfb + 128, bnfm + 128, bnfv + 128,
                                Wott, bout, out);
}

// Round 6
// 520.580 us; speedup vs baseline: 2.4027x; 2.4027x over previous
//
#include <hip/hip_runtime.h>
#include <hip/hip_bf16.h>
#include <stdint.h>

typedef unsigned short ushort_t;
typedef float   f32x4  __attribute__((ext_vector_type(4)));
typedef short   bf16x8 __attribute__((ext_vector_type(8)));

#define NSRC 8192
#define NTGT 16384
#define LDP  56   /* ushort stride (112B) for GEMM LDS tiles */

__device__ __forceinline__ ushort_t f2bf(float f){
  union { float f; uint32_t u; } v; v.f = f;
  uint32_t r = v.u + 0x7fffu + ((v.u >> 16) & 1u);
  return (ushort_t)(r >> 16);
}
__device__ __forceinline__ uint2 pack4(f32x4 v){
  uint2 r;
  r.x = (uint32_t)f2bf(v.x) | ((uint32_t)f2bf(v.y) << 16);
  r.y = (uint32_t)f2bf(v.z) | ((uint32_t)f2bf(v.w) << 16);
  return r;
}

// ---------------- generic f32 -> bf16 transpose: D[c][r] = bf16(S[r][c]) ----------------
__global__ __launch_bounds__(256) void k_wt(const float* __restrict__ S, ushort_t* __restrict__ D,
                                            int R, int C){
  __shared__ float tile[32][33];
  const int cb = blockIdx.x * 32, rb = blockIdx.y * 32;
  const int tx = threadIdx.x & 31, ty = threadIdx.x >> 5;
#pragma unroll
  for (int i = 0; i < 4; ++i)
    tile[ty + 8*i][tx] = S[(size_t)(rb + ty + 8*i) * C + cb + tx];
  __syncthreads();
#pragma unroll
  for (int i = 0; i < 4; ++i)
    D[(size_t)(cb + ty + 8*i) * R + rb + tx] = f2bf(tile[tx][ty + 8*i]);
}

// ---------------- B2t tail: row 128 = ones (colsum trick), rows 129..159 = 0 ----------------
__global__ void k_init_b2t_tail(ushort_t* __restrict__ B2t){
  int idx = blockIdx.x * 256 + threadIdx.x;     // 32*16384 total
  int r = idx >> 14;
  int k = idx & 16383;
  B2t[(size_t)(128 + r) * NTGT + k] = (r == 0) ? (ushort_t)0x3F80 : (ushort_t)0;
}

// ---------------- G1: P2[kc] = bf16(A) @ H  (BM=64, BN=256, BK=32, Ksplit=2) + rowsum ----------------
// One barrier per K-iteration: issue loads(kt+1) -> MFMA(kt) -> LDS-write(kt+1) -> barrier.
__global__ __launch_bounds__(256) void k_gemm1(const float* __restrict__ A,
    const ushort_t* __restrict__ B1t, float* __restrict__ P2, float* __restrict__ rowsumP){
  __shared__ ushort_t Asl[2][64 * LDP];
  __shared__ ushort_t Bsl[2][256 * LDP];
  const int t = threadIdx.x;
  const int mb = blockIdx.x, kc = blockIdx.y;
  const size_t m0 = (size_t)mb * 64;
  const int k0 = kc * 4096;

  const int arow = t >> 3;            // 0..31
  const int acol = (t & 7) * 4;       // 0..28
  float rs0 = 0.f, rs1 = 0.f;

  const int w = t >> 6, lane = t & 63;
  const int wr = w >> 1, wc = w & 1;
  const int fr = lane & 15, q = lane >> 4;

  int bn_[4], bk_[4];
#pragma unroll
  for (int r = 0; r < 4; ++r){
    int c = t + 256 * r; bn_[r] = c >> 2; bk_[r] = (c & 3) * 8;
  }

  f32x4 acc[2][8];
  const f32x4 vz = {0.f, 0.f, 0.f, 0.f};
#pragma unroll
  for (int i = 0; i < 2; ++i)
#pragma unroll
    for (int j = 0; j < 8; ++j) acc[i][j] = vz;

  const float* a0p = &A[(m0 + arow)      * (size_t)NSRC + k0 + acol];
  const float* a1p = &A[(m0 + 32 + arow) * (size_t)NSRC + k0 + acol];

  // prologue: tile 0 -> buf 0
  f32x4 av0 = *(const f32x4*)a0p;
  f32x4 av1 = *(const f32x4*)a1p;
  uint4 bv[4];
#pragma unroll
  for (int r = 0; r < 4; ++r)
    bv[r] = *(const uint4*)&B1t[(size_t)bn_[r] * NSRC + k0 + bk_[r]];
  rs0 += av0.x + av0.y + av0.z + av0.w;
  rs1 += av1.x + av1.y + av1.z + av1.w;
  *(uint2*)&Asl[0][arow * LDP + acol]        = pack4(av0);
  *(uint2*)&Asl[0][(32 + arow) * LDP + acol] = pack4(av1);
#pragma unroll
  for (int r = 0; r < 4; ++r) *(uint4*)&Bsl[0][bn_[r] * LDP + bk_[r]] = bv[r];
  __syncthreads();

  for (int kt = 0; kt < 128; ++kt){
    const int cur = kt & 1;
    if (kt < 127){
      const int kk = (kt + 1) * 32;
      av0 = *(const f32x4*)(a0p + kk);
      av1 = *(const f32x4*)(a1p + kk);
#pragma unroll
      for (int r = 0; r < 4; ++r)
        bv[r] = *(const uint4*)&B1t[(size_t)bn_[r] * NSRC + k0 + kk + bk_[r]];
    }

    bf16x8 af[2], bfv[8];
    af[0] = *(const bf16x8*)&Asl[cur][(wr * 32 + fr) * LDP + q * 8];
    af[1] = *(const bf16x8*)&Asl[cur][(wr * 32 + 16 + fr) * LDP + q * 8];
#pragma unroll
    for (int fn = 0; fn < 8; ++fn)
      bfv[fn] = *(const bf16x8*)&Bsl[cur][(wc * 128 + fn * 16 + fr) * LDP + q * 8];
#pragma unroll
    for (int fm = 0; fm < 2; ++fm)
#pragma unroll
      for (int fn = 0; fn < 8; ++fn)
        acc[fm][fn] = __builtin_amdgcn_mfma_f32_16x16x32_bf16(af[fm], bfv[fn], acc[fm][fn], 0, 0, 0);

    if (kt < 127){
      rs0 += av0.x + av0.y + av0.z + av0.w;
      rs1 += av1.x + av1.y + av1.z + av1.w;
      *(uint2*)&Asl[cur ^ 1][arow * LDP + acol]        = pack4(av0);
      *(uint2*)&Asl[cur ^ 1][(32 + arow) * LDP + acol] = pack4(av1);
#pragma unroll
      for (int r = 0; r < 4; ++r) *(uint4*)&Bsl[cur ^ 1][bn_[r] * LDP + bk_[r]] = bv[r];
    }
    __syncthreads();
  }

  float* Pd = P2 + (size_t)kc * NTGT * 256;
#pragma unroll
  for (int fm = 0; fm < 2; ++fm)
#pragma unroll
    for (int j = 0; j < 4; ++j){
      int row = wr * 32 + fm * 16 + q * 4 + j;
#pragma unroll
      for (int fn = 0; fn < 8; ++fn)
        Pd[(m0 + row) * 256 + wc * 128 + fn * 16 + fr] = acc[fm][fn][j];
    }

  // rowsum: 8 lanes (same arow) hold partial sums
  rs0 += __shfl_xor(rs0, 1, 8); rs0 += __shfl_xor(rs0, 2, 8); rs0 += __shfl_xor(rs0, 4, 8);
  rs1 += __shfl_xor(rs1, 1, 8); rs1 += __shfl_xor(rs1, 2, 8); rs1 += __shfl_xor(rs1, 4, 8);
  if ((t & 7) == 0){
    rowsumP[(size_t)kc * NTGT + m0 + arow]      = rs0;
    rowsumP[(size_t)kc * NTGT + m0 + 32 + arow] = rs1;
  }
}

// ---------------- G2: G2p[kc] = bf16(A)^T @ [h_tgt|1|0]  (BM=64, BN=160, BK=32, Ksplit=4) ----------------
// A^T fragment built directly in registers from column loads (no LDS for A); B double-buffered.
__global__ __launch_bounds__(256) void k_gemm2(const float* __restrict__ A,
    const ushort_t* __restrict__ B2t, float* __restrict__ G2p){
  __shared__ ushort_t Btl[2][160 * LDP];
  const int t = threadIdx.x;
  const int sb = blockIdx.x, kc = blockIdx.y;
  const size_t s0 = (size_t)sb * 64;
  const int k0 = kc * 4096;

  const int w = t >> 6, lane = t & 63;
  const int fr = lane & 15, q = lane >> 4;
  const size_t scol = s0 + w * 16 + fr;
  const int q8 = q * 8;

  int bn_[3], bk_[3];
#pragma unroll
  for (int r = 0; r < 3; ++r){
    int c = t + 256 * r; bn_[r] = c >> 2; bk_[r] = (c & 3) * 8;
  }

  f32x4 acc[10];
  const f32x4 vz = {0.f, 0.f, 0.f, 0.f};
#pragma unroll
  for (int j = 0; j < 10; ++j) acc[j] = vz;

  // prologue: tile 0
  float ar[8];
#pragma unroll
  for (int j = 0; j < 8; ++j)
    ar[j] = A[(size_t)(k0 + q8 + j) * NSRC + scol];
  uint4 bv0, bv1, bv2;
  bv0 = *(const uint4*)&B2t[(size_t)bn_[0] * NTGT + k0 + bk_[0]];
  bv1 = *(const uint4*)&B2t[(size_t)bn_[1] * NTGT + k0 + bk_[1]];
  if (t < 128) bv2 = *(const uint4*)&B2t[(size_t)bn_[2] * NTGT + k0 + bk_[2]];
  *(uint4*)&Btl[0][bn_[0] * LDP + bk_[0]] = bv0;
  *(uint4*)&Btl[0][bn_[1] * LDP + bk_[1]] = bv1;
  if (t < 128) *(uint4*)&Btl[0][bn_[2] * LDP + bk_[2]] = bv2;
  __syncthreads();

  for (int kt = 0; kt < 128; ++kt){
    const int cur = kt & 1;
    bf16x8 af;
#pragma unroll
    for (int j = 0; j < 8; ++j) af[j] = (short)f2bf(ar[j]);

    if (kt < 127){
      const int kk = k0 + (kt + 1) * 32;
#pragma unroll
      for (int j = 0; j < 8; ++j)
        ar[j] = A[(size_t)(kk + q8 + j) * NSRC + scol];
      bv0 = *(const uint4*)&B2t[(size_t)bn_[0] * NTGT + kk + bk_[0]];
      bv1 = *(const uint4*)&B2t[(size_t)bn_[1] * NTGT + kk + bk_[1]];
      if (t < 128) bv2 = *(const uint4*)&B2t[(size_t)bn_[2] * NTGT + kk + bk_[2]];
    }

#pragma unroll
    for (int fn = 0; fn < 10; ++fn){
      bf16x8 bfv = *(const bf16x8*)&Btl[cur][(fn * 16 + fr) * LDP + q * 8];
      acc[fn] = __builtin_amdgcn_mfma_f32_16x16x32_bf16(af, bfv, acc[fn], 0, 0, 0);
    }

    if (kt < 127){
      *(uint4*)&Btl[cur ^ 1][bn_[0] * LDP + bk_[0]] = bv0;
      *(uint4*)&Btl[cur ^ 1][bn_[1] * LDP + bk_[1]] = bv1;
      if (t < 128) *(uint4*)&Btl[cur ^ 1][bn_[2] * LDP + bk_[2]] = bv2;
    }
    __syncthreads();
  }

  float* Pd = G2p + (size_t)kc * NSRC * 160;
#pragma unroll
  for (int j = 0; j < 4; ++j){
    int row = w * 16 + q * 4 + j;
#pragma unroll
    for (int fn = 0; fn < 10; ++fn)
      Pd[(s0 + row) * 160 + fn * 16 + fr] = acc[fn][j];
  }
}

// ---------------- G3: G3p[kc] = bf16(A) @ h_src  (BM=64, BN=128, BK=32, Ksplit=2) ----------------
__global__ __launch_bounds__(256) void k_gemm3(const float* __restrict__ A,
    const ushort_t* __restrict__ B3t, float* __restrict__ G3p){
  __shared__ ushort_t Asl[2][64 * LDP];
  __shared__ ushort_t Bsl[2][128 * LDP];
  const int t = threadIdx.x;
  const int mb = blockIdx.x, kc = blockIdx.y;
  const size_t m0 = (size_t)mb * 64;
  const int k0 = kc * 4096;

  const int arow = t >> 3, acol = (t & 7) * 4;
  const int w = t >> 6, lane = t & 63;
  const int wr = w >> 1, wc = w & 1;
  const int fr = lane & 15, q = lane >> 4;

  int bn_[2], bk_[2];
#pragma unroll
  for (int r = 0; r < 2; ++r){
    int c = t + 256 * r; bn_[r] = c >> 2; bk_[r] = (c & 3) * 8;
  }

  f32x4 acc[2][4];
  const f32x4 vz = {0.f, 0.f, 0.f, 0.f};
#pragma unroll
  for (int i = 0; i < 2; ++i)
#pragma unroll
    for (int j = 0; j < 4; ++j) acc[i][j] = vz;

  const float* a0p = &A[(m0 + arow)      * (size_t)NSRC + k0 + acol];
  const float* a1p = &A[(m0 + 32 + arow) * (size_t)NSRC + k0 + acol];

  f32x4 av0 = *(const f32x4*)a0p;
  f32x4 av1 = *(const f32x4*)a1p;
  uint4 bv[2];
#pragma unroll
  for (int r = 0; r < 2; ++r)
    bv[r] = *(const uint4*)&B3t[(size_t)bn_[r] * NSRC + k0 + bk_[r]];
  *(uint2*)&Asl[0][arow * LDP + acol]        = pack4(av0);
  *(uint2*)&Asl[0][(32 + arow) * LDP + acol] = pack4(av1);
#pragma unroll
  for (int r = 0; r < 2; ++r) *(uint4*)&Bsl[0][bn_[r] * LDP + bk_[r]] = bv[r];
  __syncthreads();

  for (int kt = 0; kt < 128; ++kt){
    const int cur = kt & 1;
    if (kt < 127){
      const int kk = (kt + 1) * 32;
      av0 = *(const f32x4*)(a0p + kk);
      av1 = *(const f32x4*)(a1p + kk);
#pragma unroll
      for (int r = 0; r < 2; ++r)
        bv[r] = *(const uint4*)&B3t[(size_t)bn_[r] * NSRC + k0 + kk + bk_[r]];
    }

    bf16x8 af[2], bfv[4];
    af[0] = *(const bf16x8*)&Asl[cur][(wr * 32 + fr) * LDP + q * 8];
    af[1] = *(const bf16x8*)&Asl[cur][(wr * 32 + 16 + fr) * LDP + q * 8];
#pragma unroll
    for (int fn = 0; fn < 4; ++fn)
      bfv[fn] = *(const bf16x8*)&Bsl[cur][(wc * 64 + fn * 16 + fr) * LDP + q * 8];
#pragma unroll
    for (int fm = 0; fm < 2; ++fm)
#pragma unroll
      for (int fn = 0; fn < 4; ++fn)
        acc[fm][fn] = __builtin_amdgcn_mfma_f32_16x16x32_bf16(af[fm], bfv[fn], acc[fm][fn], 0, 0, 0);

    if (kt < 127){
      *(uint2*)&Asl[cur ^ 1][arow * LDP + acol]        = pack4(av0);
      *(uint2*)&Asl[cur ^ 1][(32 + arow) * LDP + acol] = pack4(av1);
#pragma unroll
      for (int r = 0; r < 2; ++r) *(uint4*)&Bsl[cur ^ 1][bn_[r] * LDP + bk_[r]] = bv[r];
    }
    __syncthreads();
  }

  float* Pd = G3p + (size_t)kc * NTGT * 128;
#pragma unroll
  for (int fm = 0; fm < 2; ++fm)
#pragma unroll
    for (int j = 0; j < 4; ++j){
      int row = wr * 32 + fm * 16 + q * 4 + j;
#pragma unroll
      for (int fn = 0; fn < 4; ++fn)
        Pd[(m0 + row) * 128 + wc * 64 + fn * 16 + fr] = acc[fm][fn][j];
    }
}

// ---------------- S1: h_tgt = relu(BN0((P/rowsum)@W0+b0)) -> B2t rows 0..127 (transposed) ----------------
__global__ __launch_bounds__(256) void k_s1(
    const float* __restrict__ P2, const float* __restrict__ rowsumP,
    const ushort_t* __restrict__ W0t, const float* __restrict__ b0,
    const float* __restrict__ g, const float* __restrict__ be,
    const float* __restrict__ mu, const float* __restrict__ va,
    ushort_t* __restrict__ B2t)
{
  __shared__ ushort_t Xs[64 * 72];
  __shared__ ushort_t Ws[128 * 72];
  __shared__ float    os[64 * 132];
  __shared__ float invs[64], scs[128], mbs[128];
  const int t = threadIdx.x;
  const size_t m0 = (size_t)blockIdx.x * 64;

  if (t < 64){
    float rsv = rowsumP[m0 + t] + rowsumP[(size_t)NTGT + m0 + t];
    invs[t] = 1.0f / fmaxf(rsv, 1e-8f);
  } else if (t < 192){
    int n = t - 64;
    float s = g[n] * rsqrtf(va[n] + 1e-5f);
    scs[n] = s;
    mbs[n] = (b0[n] - mu[n]) * s + be[n];
  }
  __syncthreads();

  const int w = t >> 6, lane = t & 63;
  const int wr = w >> 1, wc = w & 1;
  const int fr = lane & 15, q = lane >> 4;
  f32x4 acc[2][4];
  const f32x4 vz = {0.f, 0.f, 0.f, 0.f};
#pragma unroll
  for (int i = 0; i < 2; ++i)
#pragma unroll
    for (int j = 0; j < 4; ++j) acc[i][j] = vz;

  for (int kt = 0; kt < 4; ++kt){
    const int kk = kt * 64;
    __syncthreads();
#pragma unroll
    for (int r = 0; r < 4; ++r){
      int c = t + 256 * r;
      int row = c >> 4, col4 = (c & 15) * 4;
      const float* pa = &P2[(m0 + row) * 256 + kk + col4];
      f32x4 v0 = *(const f32x4*)pa;
      f32x4 v1 = *(const f32x4*)(pa + (size_t)NTGT * 256);
      f32x4 v = (v0 + v1) * invs[row];
      *(uint2*)&Xs[row * 72 + col4] = pack4(v);
    }
#pragma unroll
    for (int r = 0; r < 4; ++r){
      int c = t + 256 * r;
      int n = c >> 3, k8 = (c & 7) * 8;
      *(uint4*)&Ws[n * 72 + k8] = *(const uint4*)&W0t[(size_t)n * 256 + kk + k8];
    }
    __syncthreads();
#pragma unroll
    for (int ks = 0; ks < 2; ++ks){
      bf16x8 af[2], bfv[4];
      af[0] = *(const bf16x8*)&Xs[(wr * 32 + fr) * 72 + ks * 32 + q * 8];
      af[1] = *(const bf16x8*)&Xs[(wr * 32 + 16 + fr) * 72 + ks * 32 + q * 8];
#pragma unroll
      for (int fn = 0; fn < 4; ++fn)
        bfv[fn] = *(const bf16x8*)&Ws[(wc * 64 + fn * 16 + fr) * 72 + ks * 32 + q * 8];
#pragma unroll
      for (int fm = 0; fm < 2; ++fm)
#pragma unroll
        for (int fn = 0; fn < 4; ++fn)
          acc[fm][fn] = __builtin_amdgcn_mfma_f32_16x16x32_bf16(af[fm], bfv[fn], acc[fm][fn], 0, 0, 0);
    }
  }

#pragma unroll
  for (int fm = 0; fm < 2; ++fm)
#pragma unroll
    for (int fn = 0; fn < 4; ++fn){
      int n = wc * 64 + fn * 16 + fr;
      float s = scs[n], mb = mbs[n];
#pragma unroll
      for (int j = 0; j < 4; ++j){
        int row = wr * 32 + fm * 16 + q * 4 + j;
        os[row * 132 + n] = fmaxf(acc[fm][fn][j] * s + mb, 0.f);
      }
    }
  __syncthreads();
  {
    int nn = t >> 1, mc = (t & 1) * 32;
    ushort_t buf[32];
#pragma unroll
    for (int i = 0; i < 32; ++i) buf[i] = f2bf(os[(mc + i) * 132 + nn]);
    uint4* dst = (uint4*)&B2t[(size_t)nn * NTGT + m0 + mc];
    dst[0] = *(uint4*)&buf[0];  dst[1] = *(uint4*)&buf[8];
    dst[2] = *(uint4*)&buf[16]; dst[3] = *(uint4*)&buf[24];
  }
}

// ---------------- S2: h_src = relu(BNb((Q/colsum)@Wb0+bb0)) -> B3t (transposed) ----------------
__global__ __launch_bounds__(256) void k_s2(
    const float* __restrict__ G2p,
    const ushort_t* __restrict__ Wb0t, const float* __restrict__ bb0,
    const float* __restrict__ g, const float* __restrict__ be,
    const float* __restrict__ mu, const float* __restrict__ va,
    ushort_t* __restrict__ B3t)
{
  __shared__ ushort_t Xs[64 * 72];
  __shared__ ushort_t Ws[128 * 72];
  __shared__ float    os[64 * 132];
  __shared__ float invs[64], scs[128], mbs[128];
  const int t = threadIdx.x;
  const size_t m0 = (size_t)blockIdx.x * 64;
  const size_t CH = (size_t)NSRC * 160;

  if (t < 64){
    size_t row = m0 + t;
    float c = G2p[row * 160 + 128] + G2p[CH + row * 160 + 128]
            + G2p[2 * CH + row * 160 + 128] + G2p[3 * CH + row * 160 + 128];
    invs[t] = 1.0f / fmaxf(c, 1e-8f);
  } else if (t < 192){
    int n = t - 64;
    float s = g[n] * rsqrtf(va[n] + 1e-5f);
    scs[n] = s;
    mbs[n] = (bb0[n] - mu[n]) * s + be[n];
  }
  __syncthreads();

  const int w = t >> 6, lane = t & 63;
  const int wr = w >> 1, wc = w & 1;
  const int fr = lane & 15, q = lane >> 4;
  f32x4 acc[2][4];
  const f32x4 vz = {0.f, 0.f, 0.f, 0.f};
#pragma unroll
  for (int i = 0; i < 2; ++i)
#pragma unroll
    for (int j = 0; j < 4; ++j) acc[i][j] = vz;

  for (int kt = 0; kt < 2; ++kt){
    const int kk = kt * 64;
    __syncthreads();
#pragma unroll
    for (int r = 0; r < 4; ++r){
      int c = t + 256 * r;
      int row = c >> 4, col4 = (c & 15) * 4;
      const float* pa = &G2p[(m0 + row) * 160 + kk + col4];
      f32x4 v0 = *(const f32x4*)pa;
      f32x4 v1 = *(const f32x4*)(pa + CH);
      f32x4 v2 = *(const f32x4*)(pa + 2 * CH);
      f32x4 v3 = *(const f32x4*)(pa + 3 * CH);
      f32x4 v = (v0 + v1 + v2 + v3) * invs[row];
      *(uint2*)&Xs[row * 72 + col4] = pack4(v);
    }
#pragma unroll
    for (int r = 0; r < 4; ++r){
      int c = t + 256 * r;
      int n = c >> 3, k8 = (c & 7) * 8;
      *(uint4*)&Ws[n * 72 + k8] = *(const uint4*)&Wb0t[(size_t)n * 128 + kk + k8];
    }
    __syncthreads();
#pragma unroll
    for (int ks = 0; ks < 2; ++ks){
      bf16x8 af[2], bfv[4];
      af[0] = *(const bf16x8*)&Xs[(wr * 32 + fr) * 72 + ks * 32 + q * 8];
      af[1] = *(const bf16x8*)&Xs[(wr * 32 + 16 + fr) * 72 + ks * 32 + q * 8];
#pragma unroll
      for (int fn = 0; fn < 4; ++fn)
        bfv[fn] = *(const bf16x8*)&Ws[(wc * 64 + fn * 16 + fr) * 72 + ks * 32 + q * 8];
#pragma unroll
      for (int fm = 0; fm < 2; ++fm)
#pragma unroll
        for (int fn = 0; fn < 4; ++fn)
          acc[fm][fn] = __builtin_amdgcn_mfma_f32_16x16x32_bf16(af[fm], bfv[fn], acc[fm][fn], 0, 0, 0);
    }
  }

#pragma unroll
  for (int fm = 0; fm < 2; ++fm)
#pragma unroll
    for (int fn = 0; fn < 4; ++fn){
      int n = wc * 64 + fn * 16 + fr;
      float s = scs[n], mb = mbs[n];
#pragma unroll
      for (int j = 0; j < 4; ++j){
        int row = wr * 32 + fm * 16 + q * 4 + j;
        os[row * 132 + n] = fmaxf(acc[fm][fn][j] * s + mb, 0.f);
      }
    }
  __syncthreads();
  {
    int nn = t >> 1, mc = (t & 1) * 32;
    ushort_t buf[32];
#pragma unroll
    for (int i = 0; i < 32; ++i) buf[i] = f2bf(os[(mc + i) * 132 + nn]);
    uint4* dst = (uint4*)&B3t[(size_t)nn * NSRC + m0 + mc];
    dst[0] = *(uint4*)&buf[0];  dst[1] = *(uint4*)&buf[8];
    dst[2] = *(uint4*)&buf[16]; dst[3] = *(uint4*)&buf[24];
  }
}

// ---------------- S3: y=relu(BN1((R/rowsum)@W1+b1)); out = y@Wout + bout ----------------
__global__ __launch_bounds__(256) void k_s3(
    const float* __restrict__ G3p, const float* __restrict__ rowsumP,
    const ushort_t* __restrict__ W1t, const float* __restrict__ b1,
    const float* __restrict__ g, const float* __restrict__ be,
    const float* __restrict__ mu, const float* __restrict__ va,
    const ushort_t* __restrict__ Woutt, const float* __restrict__ bout,
    float* __restrict__ out)
{
  __shared__ ushort_t Xs[64 * 72];
  __shared__ ushort_t Ws[128 * 72];
  __shared__ ushort_t ys[64 * 136];
  __shared__ ushort_t Ws2[64 * 136];
  __shared__ float invs[64], scs[128], mbs[128];
  const int t = threadIdx.x;
  const size_t m0 = (size_t)blockIdx.x * 64;
  const size_t CH = (size_t)NTGT * 128;

  if (t < 64){
    float rsv = rowsumP[m0 + t] + rowsumP[(size_t)NTGT + m0 + t];
    invs[t] = 1.0f / fmaxf(rsv, 1e-8f);
  } else if (t < 192){
    int n = t - 64;
    float s = g[n] * rsqrtf(va[n] + 1e-5f);
    scs[n] = s;
    mbs[n] = (b1[n] - mu[n]) * s + be[n];
  }
#pragma unroll
  for (int r = 0; r < 4; ++r){
    int c = t + 256 * r;
    int n = c >> 4, k8 = (c & 15) * 8;
    *(uint4*)&Ws2[n * 136 + k8] = *(const uint4*)&Woutt[(size_t)n * 128 + k8];
  }
  __syncthreads();

  const int w = t >> 6, lane = t & 63;
  const int wr = w >> 1, wc = w & 1;
  const int fr = lane & 15, q = lane >> 4;
  f32x4 acc[2][4];
  const f32x4 vz = {0.f, 0.f, 0.f, 0.f};
#pragma unroll
  for (int i = 0; i < 2; ++i)
#pragma unroll
    for (int j = 0; j < 4; ++j) acc[i][j] = vz;

  for (int kt = 0; kt < 2; ++kt){
    const int kk = kt * 64;
    __syncthreads();
#pragma unroll
    for (int r = 0; r < 4; ++r){
      int c = t + 256 * r;
      int row = c >> 4, col4 = (c & 15) * 4;
      const float* pa = &G3p[(m0 + row) * 128 + kk + col4];
      f32x4 v0 = *(const f32x4*)pa;
      f32x4 v1 = *(const f32x4*)(pa + CH);
      f32x4 v = (v0 + v1) * invs[row];
      *(uint2*)&Xs[row * 72 + col4] = pack4(v);
    }
#pragma unroll
    for (int r = 0; r < 4; ++r){
      int c = t + 256 * r;
      int n = c >> 3, k8 = (c & 7) * 8;
      *(uint4*)&Ws[n * 72 + k8] = *(const uint4*)&W1t[(size_t)n * 128 + kk + k8];
    }
    __syncthreads();
#pragma unroll
    for (int ks = 0; ks < 2; ++ks){
      bf16x8 af[2], bfv[4];
      af[0] = *(const bf16x8*)&Xs[(wr * 32 + fr) * 72 + ks * 32 + q * 8];
      af[1] = *(const bf16x8*)&Xs[(wr * 32 + 16 + fr) * 72 + ks * 32 + q * 8];
#pragma unroll
      for (int fn = 0; fn < 4; ++fn)
        bfv[fn] = *(const bf16x8*)&Ws[(wc * 64 + fn * 16 + fr) * 72 + ks * 32 + q * 8];
#pragma unroll
      for (int fm = 0; fm < 2; ++fm)
#pragma unroll
        for (int fn = 0; fn < 4; ++fn)
          acc[fm][fn] = __builtin_amdgcn_mfma_f32_16x16x32_bf16(af[fm], bfv[fn], acc[fm][fn], 0, 0, 0);
    }
  }

#pragma unroll
  for (int fm = 0; fm < 2; ++fm)
#pragma unroll
    for (int fn = 0; fn < 4; ++fn){
      int n = wc * 64 + fn * 16 + fr;
      float s = scs[n], mb = mbs[n];
#pragma unroll
      for (int j = 0; j < 4; ++j){
        int row = wr * 32 + fm * 16 + q * 4 + j;
        ys[row * 136 + n] = f2bf(fmaxf(acc[fm][fn][j] * s + mb, 0.f));
      }
    }
  __syncthreads();

  f32x4 acc2[2][2];
#pragma unroll
  for (int i = 0; i < 2; ++i)
#pragma unroll
    for (int j = 0; j < 2; ++j) acc2[i][j] = vz;
#pragma unroll
  for (int ks = 0; ks < 4; ++ks){
    bf16x8 af[2], bfv[2];
    af[0] = *(const bf16x8*)&ys[(wr * 32 + fr) * 136 + ks * 32 + q * 8];
    af[1] = *(const bf16x8*)&ys[(wr * 32 + 16 + fr) * 136 + ks * 32 + q * 8];
#pragma unroll
    for (int fn = 0; fn < 2; ++fn)
      bfv[fn] = *(const bf16x8*)&Ws2[(wc * 32 + fn * 16 + fr) * 136 + ks * 32 + q * 8];
#pragma unroll
    for (int fm = 0; fm < 2; ++fm)
#pragma unroll
      for (int fn = 0; fn < 2; ++fn)
        acc2[fm][fn] = __builtin_amdgcn_mfma_f32_16x16x32_bf16(af[fm], bfv[fn], acc2[fm][fn], 0, 0, 0);
  }
#pragma unroll
  for (int fm = 0; fm < 2; ++fm)
#pragma unroll
    for (int fn = 0; fn < 2; ++fn){
      int n = wc * 32 + fn * 16 + fr;
      float bo = bout[n];
#pragma unroll
      for (int j = 0; j < 4; ++j){
        int row = wr * 32 + fm * 16 + q * 4 + j;
        out[(m0 + row) * 64 + n] = acc2[fm][fn][j] + bo;
      }
    }
}

// ---------------- launch ----------------
extern "C" void kernel_launch(void* const* d_in, const int* in_sizes, int n_in,
                              void* d_out, int out_size, void* d_ws, size_t ws_size,
                              hipStream_t stream) {
  const float* Hs  = (const float*)d_in[0];
  const float* A   = (const float*)d_in[2];
  const float* W0  = (const float*)d_in[3];
  const float* b0  = (const float*)d_in[4];
  const float* Wb0 = (const float*)d_in[5];
  const float* bb0 = (const float*)d_in[6];
  const float* W1  = (const float*)d_in[7];
  const float* b1  = (const float*)d_in[8];
  const float* bnfg= (const float*)d_in[9];
  const float* bnfb= (const float*)d_in[10];
  const float* bnfm= (const float*)d_in[11];
  const float* bnfv= (const float*)d_in[12];
  const float* bnbg= (const float*)d_in[13];
  const float* bnbb= (const float*)d_in[14];
  const float* bnbm= (const float*)d_in[15];
  const float* bnbv= (const float*)d_in[16];
  const float* Wout= (const float*)d_in[17];
  const float* bout= (const float*)d_in[18];
  float* out = (float*)d_out;

  char* ws = (char*)d_ws;
  // region R1 (32MB) shared sequentially by P2 (32MB) -> G2p (21MB) -> G3p (16.8MB)
  float*    R1    = (float*)ws;
  constexpr size_t OFF_B1T  = 33554432;               // P2 max: 2*16384*256*4
  constexpr size_t OFF_B2T  = OFF_B1T + 4194304;      // B1t: 256*8192*2
  constexpr size_t OFF_B3T  = OFF_B2T + 5242880;      // B2t: 160*16384*2
  constexpr size_t OFF_RS   = OFF_B3T + 2097152;      // B3t: 128*8192*2
  constexpr size_t OFF_W0T  = OFF_RS  + 131072;       // rs: 2*16384*4
  constexpr size_t OFF_WB0T = OFF_W0T + 65536;
  constexpr size_t OFF_W1T  = OFF_WB0T + 32768;
  constexpr size_t OFF_WOT  = OFF_W1T + 32768;
  ushort_t* B1t  = (ushort_t*)(ws + OFF_B1T);
  ushort_t* B2t  = (ushort_t*)(ws + OFF_B2T);
  ushort_t* B3t  = (ushort_t*)(ws + OFF_B3T);
  float*    rsP  = (float*)   (ws + OFF_RS);
  ushort_t* W0t  = (ushort_t*)(ws + OFF_W0T);
  ushort_t* Wb0t = (ushort_t*)(ws + OFF_WB0T);
  ushort_t* W1t  = (ushort_t*)(ws + OFF_W1T);
  ushort_t* Wott = (ushort_t*)(ws + OFF_WOT);

  k_wt<<<dim3(256/32, 8192/32), 256, 0, stream>>>(Hs,  B1t, 8192, 256);
  k_wt<<<dim3(128/32, 256/32),  256, 0, stream>>>(W0,  W0t, 256, 128);
  k_wt<<<dim3(128/32, 128/32),  256, 0, stream>>>(Wb0, Wb0t, 128, 128);
  k_wt<<<dim3(128/32, 128/32),  256, 0, stream>>>(W1,  W1t, 128, 128);
  k_wt<<<dim3(64/32, 128/32),   256, 0, stream>>>(Wout, Wott, 128, 64);
  k_init_b2t_tail<<<2048, 256, 0, stream>>>(B2t);

  k_gemm1<<<dim3(256, 2), 256, 0, stream>>>(A, B1t, R1, rsP);
  k_s1<<<256, 256, 0, stream>>>(R1, rsP, W0t, b0, bnfg, bnfb, bnfm, bnfv, B2t);
  k_gemm2<<<dim3(128, 4), 256, 0, stream>>>(A, B2t, R1);
  k_s2<<<128, 256, 0, stream>>>(R1, Wb0t, bb0, bnbg, bnbb, bnbm, bnbv, B3t);
  k_gemm3<<<dim3(256, 2), 256, 0, stream>>>(A, B3t, R1);
  k_s3<<<256, 256, 0, stream>>>(R1, rsP, W1t, b1, bnfg + 128, bnfb + 128, bnfm + 128, bnfv + 128,
                                Wott, bout, out);
}